// Round 1
// baseline (367.790 us; speedup 1.0000x reference)
//
#include <hip/hip_runtime.h>

// f16 pipeline: convert/transpose -> QKV proj GEMM -> flash attn (S^T trick,
// P stays in registers via mfma_f32_16x16x16f16 B-layout match) -> out GEMM.
// Workspace: 102,760,448 bytes.

typedef _Float16 f16;
typedef _Float16 f16x4 __attribute__((ext_vector_type(4)));
typedef _Float16 f16x8 __attribute__((ext_vector_type(8)));
typedef float f32x4 __attribute__((ext_vector_type(4)));

#define D_MODEL 512
#define HD 64
#define SEQ 2048

// ---------------------------------------------------------------- K0: fp32 [b][c][n] -> f16 XT [src][b][n][c]
__global__ __launch_bounds__(256) void k_transpose(
    const float* __restrict__ q, const float* __restrict__ k, const float* __restrict__ v,
    f16* __restrict__ XT)
{
  __shared__ __align__(16) f16 Ts[64][72];
  int t = threadIdx.x;
  int nt = blockIdx.x, ct = blockIdx.y, z = blockIdx.z;
  int src = z >> 3, b = z & 7;
  const float* S = (src == 0) ? q : (src == 1) ? k : v;
  {
    int cr = t >> 2, ns = t & 3;
    const float* p = S + ((size_t)b * D_MODEL + ct * 64 + cr) * SEQ + nt * 64 + ns * 16;
    f32x4 a0 = *(const f32x4*)(p);
    f32x4 a1 = *(const f32x4*)(p + 4);
    f32x4 a2 = *(const f32x4*)(p + 8);
    f32x4 a3 = *(const f32x4*)(p + 12);
    f16x8 h0, h1;
#pragma unroll
    for (int j = 0; j < 4; ++j) { h0[j] = (f16)a0[j]; h0[4 + j] = (f16)a1[j]; h1[j] = (f16)a2[j]; h1[4 + j] = (f16)a3[j]; }
    *(f16x8*)&Ts[cr][ns * 16] = h0;
    *(f16x8*)&Ts[cr][ns * 16 + 8] = h1;
  }
  __syncthreads();
  {
    int nr = t >> 2, cs = t & 3;
    f16x8 h0, h1;
#pragma unroll
    for (int j = 0; j < 8; ++j) h0[j] = Ts[cs * 16 + j][nr];
#pragma unroll
    for (int j = 0; j < 8; ++j) h1[j] = Ts[cs * 16 + 8 + j][nr];
    f16* dst = XT + (((size_t)z) * SEQ + nt * 64 + nr) * D_MODEL + ct * 64 + cs * 16;
    *(f16x8*)dst = h0;
    *(f16x8*)(dst + 8) = h1;
  }
}

// ---------------------------------------------------------------- K0b: weights -> f16 (+ per-head shuffle of Wm)
__global__ __launch_bounds__(256) void k_wconv(
    const float* __restrict__ Wq, const float* __restrict__ Wk, const float* __restrict__ Wv,
    const float* __restrict__ Wm, f16* __restrict__ W3, f16* __restrict__ Wmh)
{
  int idx = blockIdx.x * 256 + threadIdx.x;
  if (idx < 262144) {
    W3[idx] = (f16)Wq[idx];
    W3[262144 + idx] = (f16)Wk[idx];
    W3[524288 + idx] = (f16)Wv[idx];
    int o = idx >> 9, c = idx & 511;
    int h = c & 7, d = c >> 3;             // c = d*8 + h  (reshape(B, HD, H, N))
    Wmh[((size_t)h * 512 + o) * 64 + d] = (f16)Wm[idx];
  }
}

// ---------------------------------------------------------------- K1: QKV projection GEMM, head-split epilogue
// out = W[o][c] @ XT^T + b ; Q/K written [b][h][n][d], V written [b][h][d][m]
__global__ __launch_bounds__(256, 2) void k_proj(
    const f16* __restrict__ W3, const float* __restrict__ bq, const float* __restrict__ bk,
    const float* __restrict__ bv, const f16* __restrict__ XT,
    f16* __restrict__ Qt, f16* __restrict__ Kt, f16* __restrict__ Vh)
{
  __shared__ __align__(16) char smem[34816];
  f16 (*As)[40] = (f16(*)[40])smem;                 // [128][32+8]
  f16 (*Bs)[40] = (f16(*)[40])(smem + 10240);
  f16 (*Ls)[136] = (f16(*)[136])smem;               // epilogue tile [128][128+8]

  int t = threadIdx.x;
  int proj = blockIdx.z, b = blockIdx.y;
  int ot = blockIdx.x & 3, ntile = blockIdx.x >> 2;
  int w = t >> 6, ln = t & 63, i16 = ln & 15, q4 = ln >> 4;
  int ow = w >> 1, nw = w & 1;

  const f16* Wp = W3 + (size_t)proj * 262144;
  const f16* Xp = XT + ((size_t)proj * 8 + b) * (size_t)SEQ * D_MODEL;

  f32x4 acc[4][4];
#pragma unroll
  for (int x = 0; x < 4; ++x)
#pragma unroll
    for (int y = 0; y < 4; ++y) acc[x][y] = (f32x4){0.f, 0.f, 0.f, 0.f};

  int srow = t >> 1, sseg = t & 1;
  for (int kc = 0; kc < 16; ++kc) {
    __syncthreads();
    const f16* Ap = Wp + ((size_t)(ot * 128 + srow)) * 512 + kc * 32 + sseg * 16;
    *(f32x4*)&As[srow][sseg * 16] = *(const f32x4*)(Ap);
    *(f32x4*)&As[srow][sseg * 16 + 8] = *(const f32x4*)(Ap + 8);
    const f16* Bp = Xp + ((size_t)(ntile * 128 + srow)) * 512 + kc * 32 + sseg * 16;
    *(f32x4*)&Bs[srow][sseg * 16] = *(const f32x4*)(Bp);
    *(f32x4*)&Bs[srow][sseg * 16 + 8] = *(const f32x4*)(Bp + 8);
    __syncthreads();
    f16x8 af[4], bf[4];
#pragma unroll
    for (int x = 0; x < 4; ++x) af[x] = *(const f16x8*)&As[ow * 64 + x * 16 + i16][q4 * 8];
#pragma unroll
    for (int y = 0; y < 4; ++y) bf[y] = *(const f16x8*)&Bs[nw * 64 + y * 16 + i16][q4 * 8];
#pragma unroll
    for (int x = 0; x < 4; ++x)
#pragma unroll
      for (int y = 0; y < 4; ++y)
        acc[x][y] = __builtin_amdgcn_mfma_f32_16x16x32_f16(af[x], bf[y], acc[x][y], 0, 0, 0);
  }

  const float* bias = (proj == 0) ? bq : (proj == 1) ? bk : bv;
  __syncthreads();
#pragma unroll
  for (int x = 0; x < 4; ++x) {
    f32x4 bb = *(const f32x4*)(bias + ot * 128 + ow * 64 + x * 16 + q4 * 4);
#pragma unroll
    for (int y = 0; y < 4; ++y)
#pragma unroll
      for (int r = 0; r < 4; ++r)
        Ls[ow * 64 + x * 16 + q4 * 4 + r][nw * 64 + y * 16 + i16] = (f16)(acc[x][y][r] + bb[r]);
  }
  __syncthreads();
  if (proj < 2) {
    // o = 8*d + h ; write [b][h][n][d] (d-contiguous 32B runs)
    f16* dst = (proj == 0) ? Qt : Kt;
#pragma unroll
    for (int rnd = 0; rnd < 4; ++rnd) {
      int task = rnd * 256 + t;
      int nl = task & 127, h = task >> 7;
      f16x8 g0, g1;
#pragma unroll
      for (int j = 0; j < 8; ++j) g0[j] = Ls[8 * j + h][nl];
#pragma unroll
      for (int j = 0; j < 8; ++j) g1[j] = Ls[8 * (8 + j) + h][nl];
      f16* dp = dst + (((size_t)(b * 8 + h)) * SEQ + ntile * 128 + nl) * HD + ot * 16;
      *(f16x8*)dp = g0;
      *(f16x8*)(dp + 8) = g1;
    }
  } else {
    // V: write rows [b][h][d][m] (m-contiguous)
#pragma unroll
    for (int p = 0; p < 8; ++p) {
      int ol = (t >> 4) + 16 * p;
      int ch = t & 15;
      int og = ot * 128 + ol;
      int h = og & 7, d = og >> 3;
      f16* dp = Vh + (((size_t)(b * 8 + h)) * HD + d) * SEQ + ntile * 128 + ch * 8;
      *(f32x4*)dp = *(const f32x4*)&Ls[ol][ch * 8];
    }
  }
}

// ---------------------------------------------------------------- K2: flash attention (S^T; P in regs -> 16x16x16 PV)
__global__ __launch_bounds__(256, 2) void k_attn(
    const f16* __restrict__ Qt, const f16* __restrict__ Kt, const f16* __restrict__ Vh,
    const float* __restrict__ qmask, const float* __restrict__ kvmask,
    f16* __restrict__ O)
{
  __shared__ __align__(16) char smem[55552];
  f16 (*Qs)[72] = (f16(*)[72])smem;                 // [256][64+8]
  f16 (*Ks)[72] = (f16(*)[72])(smem + 36864);       // [64][72]
  f16 (*Vs)[72] = (f16(*)[72])(smem + 46080);       // [64][72]
  float* kvb = (float*)(smem + 55296);              // [64]

  int t = threadIdx.x;
  int bh = blockIdx.x >> 3;
  int b = bh >> 3;
  int n0 = (blockIdx.x & 7) * 256;
  int w = t >> 6, ln = t & 63, i16 = ln & 15, q4 = ln >> 4;

  const f16* Qb = Qt + (size_t)bh * SEQ * HD;
  const f16* Kb = Kt + (size_t)bh * SEQ * HD;
  const f16* Vb = Vh + (size_t)bh * HD * SEQ;

#pragma unroll
  for (int p = 0; p < 8; ++p) {
    int row = (t >> 3) + 32 * p, ch = t & 7;
    *(f32x4*)&Qs[row][ch * 8] = *(const f32x4*)(Qb + ((size_t)(n0 + row)) * HD + ch * 8);
  }
  __syncthreads();
  f16x8 qf[4][2];
#pragma unroll
  for (int nt = 0; nt < 4; ++nt)
#pragma unroll
    for (int kc = 0; kc < 2; ++kc)
      qf[nt][kc] = *(const f16x8*)&Qs[w * 64 + nt * 16 + i16][kc * 32 + q4 * 8];
  float qok[4];
#pragma unroll
  for (int nt = 0; nt < 4; ++nt)
    qok[nt] = qmask[(size_t)b * SEQ + n0 + w * 64 + nt * 16 + i16];

  f32x4 acc_o[4][4];  // [dt][nt] — O^T fragments
#pragma unroll
  for (int dt = 0; dt < 4; ++dt)
#pragma unroll
    for (int nt = 0; nt < 4; ++nt) acc_o[dt][nt] = (f32x4){0.f, 0.f, 0.f, 0.f};
  float m_i[4] = {-3e38f, -3e38f, -3e38f, -3e38f};
  float l_i[4] = {0.f, 0.f, 0.f, 0.f};

  for (int it = 0; it < 32; ++it) {
    int m0 = it * 64;
    __syncthreads();
#pragma unroll
    for (int p = 0; p < 2; ++p) {
      int row = (t >> 3) + 32 * p, ch = t & 7;
      *(f32x4*)&Ks[row][ch * 8] = *(const f32x4*)(Kb + ((size_t)(m0 + row)) * HD + ch * 8);
      *(f32x4*)&Vs[row][ch * 8] = *(const f32x4*)(Vb + ((size_t)row) * SEQ + m0 + ch * 8);
    }
    if (t < 64) {
      float kv = kvmask[(size_t)b * SEQ + m0 + t];
      kvb[t] = (kv > 0.f) ? 0.f : -1e9f;
    }
    __syncthreads();

    f16x8 kf[4][2];
#pragma unroll
    for (int mt = 0; mt < 4; ++mt)
#pragma unroll
      for (int kc = 0; kc < 2; ++kc)
        kf[mt][kc] = *(const f16x8*)&Ks[mt * 16 + i16][kc * 32 + q4 * 8];

    // S^T[m][n]: rows = key pos (quad*4+reg), col = query pos (lane&15)
    f32x4 st[4][4];
#pragma unroll
    for (int mt = 0; mt < 4; ++mt)
#pragma unroll
      for (int nt = 0; nt < 4; ++nt) {
        f32x4 a = (f32x4){0.f, 0.f, 0.f, 0.f};
        a = __builtin_amdgcn_mfma_f32_16x16x32_f16(kf[mt][0], qf[nt][0], a, 0, 0, 0);
        a = __builtin_amdgcn_mfma_f32_16x16x32_f16(kf[mt][1], qf[nt][1], a, 0, 0, 0);
        st[mt][nt] = a;
      }

    f32x4 kvf[4];
#pragma unroll
    for (int mt = 0; mt < 4; ++mt) kvf[mt] = *(const f32x4*)&kvb[mt * 16 + q4 * 4];

    f16x4 pf[4][4];  // [mt][nt] — B-fragments for 16x16x16 PV, straight from C-layout
    float al[4];
#pragma unroll
    for (int nt = 0; nt < 4; ++nt) {
      float mx = -3e38f;
#pragma unroll
      for (int mt = 0; mt < 4; ++mt)
#pragma unroll
        for (int r = 0; r < 4; ++r) {
          float sv = st[mt][nt][r] * 0.125f + kvf[mt][r];
          sv = (qok[nt] > 0.f) ? sv : -1e9f;
          st[mt][nt][r] = sv;
          mx = fmaxf(mx, sv);
        }
      mx = fmaxf(mx, __shfl_xor(mx, 16, 64));
      mx = fmaxf(mx, __shfl_xor(mx, 32, 64));
      float mnew = fmaxf(m_i[nt], mx);
      float alpha = __expf(m_i[nt] - mnew);
      float rsum = 0.f;
#pragma unroll
      for (int mt = 0; mt < 4; ++mt) {
        f16x4 pv;
#pragma unroll
        for (int r = 0; r < 4; ++r) {
          float pe = __expf(st[mt][nt][r] - mnew);
          rsum += pe;
          pv[r] = (f16)pe;
        }
        pf[mt][nt] = pv;
      }
      rsum += __shfl_xor(rsum, 16, 64);
      rsum += __shfl_xor(rsum, 32, 64);
      l_i[nt] = l_i[nt] * alpha + rsum;
      m_i[nt] = mnew;
      al[nt] = alpha;
    }

    f16x4 vf[4][4];  // [dt][mt] — A-fragments (V^T)
#pragma unroll
    for (int dt = 0; dt < 4; ++dt)
#pragma unroll
      for (int mt = 0; mt < 4; ++mt)
        vf[dt][mt] = *(const f16x4*)&Vs[dt * 16 + i16][mt * 16 + q4 * 4];

#pragma unroll
    for (int dt = 0; dt < 4; ++dt)
#pragma unroll
      for (int nt = 0; nt < 4; ++nt) {
        f32x4 o = acc_o[dt][nt];
        float a = al[nt];
#pragma unroll
        for (int r = 0; r < 4; ++r) o[r] *= a;
#pragma unroll
        for (int mt = 0; mt < 4; ++mt)
          o = __builtin_amdgcn_mfma_f32_16x16x16f16(vf[dt][mt], pf[mt][nt], o, 0, 0, 0);
        acc_o[dt][nt] = o;
      }
  }

  // epilogue: normalize, LDS transpose, coalesced 128B row stores of O[b][h][n][d]
  __syncthreads();
  f16 (*Os)[72] = (f16(*)[72])(smem + w * 9216);
#pragma unroll
  for (int nt = 0; nt < 4; ++nt) {
    float inv = 1.f / l_i[nt];
#pragma unroll
    for (int dt = 0; dt < 4; ++dt) {
      f16x4 o4;
#pragma unroll
      for (int r = 0; r < 4; ++r) o4[r] = (f16)(acc_o[dt][nt][r] * inv);
      *(f16x4*)&Os[nt * 16 + i16][dt * 16 + q4 * 4] = o4;
    }
  }
  __syncthreads();
  f16* Ob = O + ((size_t)bh * SEQ + n0 + w * 64) * HD;
#pragma unroll
  for (int p = 0; p < 8; ++p) {
    int row = (ln >> 3) + 8 * p, ch = ln & 7;
    *(f32x4*)(Ob + (size_t)row * HD + ch * 8) = *(const f32x4*)&Os[row][ch * 8];
  }
}

// ---------------------------------------------------------------- K3: out = sum_h Wmh[h] @ O_h + bm  (fp32 out)
__global__ __launch_bounds__(256, 2) void k_out(
    const f16* __restrict__ Wmh, const float* __restrict__ bm,
    const f16* __restrict__ O, float* __restrict__ out)
{
  __shared__ __align__(16) char smem[20480];
  f16 (*As)[40] = (f16(*)[40])smem;
  f16 (*Bs)[40] = (f16(*)[40])(smem + 10240);

  int t = threadIdx.x;
  int b = blockIdx.y;
  int ot = blockIdx.x & 3, ntile = blockIdx.x >> 2;
  int w = t >> 6, ln = t & 63, i16 = ln & 15, q4 = ln >> 4;
  int ow = w >> 1, nw = w & 1;

  f32x4 acc[4][4];
#pragma unroll
  for (int x = 0; x < 4; ++x)
#pragma unroll
    for (int y = 0; y < 4; ++y) acc[x][y] = (f32x4){0.f, 0.f, 0.f, 0.f};

  int srow = t >> 1, sseg = t & 1;
  for (int ck = 0; ck < 16; ++ck) {
    int h = ck >> 1, dc = ck & 1;
    __syncthreads();
    const f16* Ap = Wmh + ((size_t)h * 512 + ot * 128 + srow) * 64 + dc * 32 + sseg * 16;
    *(f32x4*)&As[srow][sseg * 16] = *(const f32x4*)(Ap);
    *(f32x4*)&As[srow][sseg * 16 + 8] = *(const f32x4*)(Ap + 8);
    const f16* Bp = O + (((size_t)(b * 8 + h)) * SEQ + ntile * 128 + srow) * 64 + dc * 32 + sseg * 16;
    *(f32x4*)&Bs[srow][sseg * 16] = *(const f32x4*)(Bp);
    *(f32x4*)&Bs[srow][sseg * 16 + 8] = *(const f32x4*)(Bp + 8);
    __syncthreads();
    f16x8 af[4], bf[4];
#pragma unroll
    for (int x = 0; x < 4; ++x) af[x] = *(const f16x8*)&As[ow * 64 + x * 16 + i16][q4 * 8];
#pragma unroll
    for (int y = 0; y < 4; ++y) bf[y] = *(const f16x8*)&Bs[nw * 64 + y * 16 + i16][q4 * 8];
#pragma unroll
    for (int x = 0; x < 4; ++x)
#pragma unroll
      for (int y = 0; y < 4; ++y)
        acc[x][y] = __builtin_amdgcn_mfma_f32_16x16x32_f16(af[x], bf[y], acc[x][y], 0, 0, 0);
  }

#pragma unroll
  for (int x = 0; x < 4; ++x) {
    f32x4 bb = *(const f32x4*)(bm + ot * 128 + ow * 64 + x * 16 + q4 * 4);
#pragma unroll
    for (int y = 0; y < 4; ++y)
#pragma unroll
      for (int r = 0; r < 4; ++r) {
        int o_g = ot * 128 + ow * 64 + x * 16 + q4 * 4 + r;
        int n_g = ntile * 128 + nw * 64 + y * 16 + i16;
        out[((size_t)b * 512 + o_g) * SEQ + n_g] = acc[x][y][r] + bb[r];
      }
  }
}

// ----------------------------------------------------------------
extern "C" void kernel_launch(void* const* d_in, const int* in_sizes, int n_in,
                              void* d_out, int out_size, void* d_ws, size_t ws_size,
                              hipStream_t stream)
{
  const float* query  = (const float*)d_in[0];
  const float* key    = (const float*)d_in[1];
  const float* value  = (const float*)d_in[2];
  const float* qmask  = (const float*)d_in[3];
  const float* kvmask = (const float*)d_in[4];
  const float* Wq = (const float*)d_in[5];
  const float* bq = (const float*)d_in[6];
  const float* Wk = (const float*)d_in[7];
  const float* bk = (const float*)d_in[8];
  const float* Wv = (const float*)d_in[9];
  const float* bv = (const float*)d_in[10];
  const float* Wm = (const float*)d_in[11];
  const float* bm = (const float*)d_in[12];
  float* out = (float*)d_out;

  char* ws = (char*)d_ws;
  f16* XT  = (f16*)(ws);                  // [3][8][2048][512]  50,331,648 B
  f16* Qt  = (f16*)(ws + 50331648);       // [8][8][2048][64]   16,777,216 B
  f16* Kt  = (f16*)(ws + 67108864);
  f16* Vh  = (f16*)(ws + 83886080);       // [8][8][64][2048]
  f16* Oat = (f16*)(ws);                  // alias XT_q region (XT dead after k_proj)
  f16* W3  = (f16*)(ws + 100663296);      // [3][512][512]       1,572,864 B
  f16* Wmh = (f16*)(ws + 102236160);      // [8][512][64]          524,288 B

  k_transpose<<<dim3(32, 8, 24), 256, 0, stream>>>(query, key, value, XT);
  k_wconv<<<1024, 256, 0, stream>>>(Wq, Wk, Wv, Wm, W3, Wmh);
  k_proj<<<dim3(64, 8, 3), 256, 0, stream>>>(W3, bq, bk, bv, XT, Qt, Kt, Vh);
  k_attn<<<512, 256, 0, stream>>>(Qt, Kt, Vh, qmask, kvmask, Oat);
  k_out<<<dim3(64, 8), 256, 0, stream>>>(Wmh, bm, Oat, out);
}

// Round 3
// 356.060 us; speedup vs baseline: 1.0329x; 1.0329x over previous
//
#include <hip/hip_runtime.h>

// f16 pipeline: convert/transpose -> QKV proj GEMM (Q pre-scaled by 0.125*log2e)
// -> flash attn (S^T trick, P in regs via mfma_16x16x16f16 B-layout; exp2 domain,
// kv-bias via MFMA C-init, 128-row q-blocks for occupancy) -> out GEMM.
// Workspace: 102,760,448 bytes.

typedef _Float16 f16;
typedef _Float16 f16x4 __attribute__((ext_vector_type(4)));
typedef _Float16 f16x8 __attribute__((ext_vector_type(8)));
typedef float f32x4 __attribute__((ext_vector_type(4)));

#define D_MODEL 512
#define HD 64
#define SEQ 2048
#define QSCL 0.18033688011112042f   // 0.125 * log2(e)
#define KVNEG -1.4426950409e9f      // -1e9 * log2(e)

// ---------------------------------------------------------------- K0: fp32 [b][c][n] -> f16 XT [src][b][n][c]
__global__ __launch_bounds__(256) void k_transpose(
    const float* __restrict__ q, const float* __restrict__ k, const float* __restrict__ v,
    f16* __restrict__ XT)
{
  __shared__ __align__(16) f16 Ts[64][72];
  int t = threadIdx.x;
  int nt = blockIdx.x, ct = blockIdx.y, z = blockIdx.z;
  int src = z >> 3, b = z & 7;
  const float* S = (src == 0) ? q : (src == 1) ? k : v;
  {
    int cr = t >> 2, ns = t & 3;
    const float* p = S + ((size_t)b * D_MODEL + ct * 64 + cr) * SEQ + nt * 64 + ns * 16;
    f32x4 a0 = *(const f32x4*)(p);
    f32x4 a1 = *(const f32x4*)(p + 4);
    f32x4 a2 = *(const f32x4*)(p + 8);
    f32x4 a3 = *(const f32x4*)(p + 12);
    f16x8 h0, h1;
#pragma unroll
    for (int j = 0; j < 4; ++j) { h0[j] = (f16)a0[j]; h0[4 + j] = (f16)a1[j]; h1[j] = (f16)a2[j]; h1[4 + j] = (f16)a3[j]; }
    *(f16x8*)&Ts[cr][ns * 16] = h0;
    *(f16x8*)&Ts[cr][ns * 16 + 8] = h1;
  }
  __syncthreads();
  {
    int nr = t >> 2, cs = t & 3;
    f16x8 h0, h1;
#pragma unroll
    for (int j = 0; j < 8; ++j) h0[j] = Ts[cs * 16 + j][nr];
#pragma unroll
    for (int j = 0; j < 8; ++j) h1[j] = Ts[cs * 16 + 8 + j][nr];
    f16* dst = XT + (((size_t)z) * SEQ + nt * 64 + nr) * D_MODEL + ct * 64 + cs * 16;
    *(f16x8*)dst = h0;
    *(f16x8*)(dst + 8) = h1;
  }
}

// ---------------------------------------------------------------- K0b: weights -> f16 (+ per-head shuffle of Wm)
__global__ __launch_bounds__(256) void k_wconv(
    const float* __restrict__ Wq, const float* __restrict__ Wk, const float* __restrict__ Wv,
    const float* __restrict__ Wm, f16* __restrict__ W3, f16* __restrict__ Wmh)
{
  int idx = blockIdx.x * 256 + threadIdx.x;
  if (idx < 262144) {
    W3[idx] = (f16)Wq[idx];
    W3[262144 + idx] = (f16)Wk[idx];
    W3[524288 + idx] = (f16)Wv[idx];
    int o = idx >> 9, c = idx & 511;
    int h = c & 7, d = c >> 3;             // c = d*8 + h  (reshape(B, HD, H, N))
    Wmh[((size_t)h * 512 + o) * 64 + d] = (f16)Wm[idx];
  }
}

// ---------------------------------------------------------------- K1: QKV projection GEMM, head-split epilogue
// out = W[o][c] @ XT^T + b ; Q/K written [b][h][n][d] (Q pre-scaled), V written [b][h][d][m]
__global__ __launch_bounds__(256, 2) void k_proj(
    const f16* __restrict__ W3, const float* __restrict__ bq, const float* __restrict__ bk,
    const float* __restrict__ bv, const f16* __restrict__ XT,
    f16* __restrict__ Qt, f16* __restrict__ Kt, f16* __restrict__ Vh)
{
  __shared__ __align__(16) char smem[34816];
  f16 (*As)[40] = (f16(*)[40])smem;                 // [128][32+8]
  f16 (*Bs)[40] = (f16(*)[40])(smem + 10240);
  f16 (*Ls)[136] = (f16(*)[136])smem;               // epilogue tile [128][128+8]

  int t = threadIdx.x;
  int proj = blockIdx.z, b = blockIdx.y;
  int ot = blockIdx.x & 3, ntile = blockIdx.x >> 2;
  int w = t >> 6, ln = t & 63, i16 = ln & 15, q4 = ln >> 4;
  int ow = w >> 1, nw = w & 1;

  const f16* Wp = W3 + (size_t)proj * 262144;
  const f16* Xp = XT + ((size_t)proj * 8 + b) * (size_t)SEQ * D_MODEL;

  f32x4 acc[4][4];
#pragma unroll
  for (int x = 0; x < 4; ++x)
#pragma unroll
    for (int y = 0; y < 4; ++y) acc[x][y] = (f32x4){0.f, 0.f, 0.f, 0.f};

  int srow = t >> 1, sseg = t & 1;
  for (int kc = 0; kc < 16; ++kc) {
    __syncthreads();
    const f16* Ap = Wp + ((size_t)(ot * 128 + srow)) * 512 + kc * 32 + sseg * 16;
    *(f32x4*)&As[srow][sseg * 16] = *(const f32x4*)(Ap);
    *(f32x4*)&As[srow][sseg * 16 + 8] = *(const f32x4*)(Ap + 8);
    const f16* Bp = Xp + ((size_t)(ntile * 128 + srow)) * 512 + kc * 32 + sseg * 16;
    *(f32x4*)&Bs[srow][sseg * 16] = *(const f32x4*)(Bp);
    *(f32x4*)&Bs[srow][sseg * 16 + 8] = *(const f32x4*)(Bp + 8);
    __syncthreads();
    f16x8 af[4], bf[4];
#pragma unroll
    for (int x = 0; x < 4; ++x) af[x] = *(const f16x8*)&As[ow * 64 + x * 16 + i16][q4 * 8];
#pragma unroll
    for (int y = 0; y < 4; ++y) bf[y] = *(const f16x8*)&Bs[nw * 64 + y * 16 + i16][q4 * 8];
#pragma unroll
    for (int x = 0; x < 4; ++x)
#pragma unroll
      for (int y = 0; y < 4; ++y)
        acc[x][y] = __builtin_amdgcn_mfma_f32_16x16x32_f16(af[x], bf[y], acc[x][y], 0, 0, 0);
  }

  const float* bias = (proj == 0) ? bq : (proj == 1) ? bk : bv;
  float scl = (proj == 0) ? QSCL : 1.0f;   // fold 0.125*log2e into Q
  __syncthreads();
#pragma unroll
  for (int x = 0; x < 4; ++x) {
    f32x4 bb = *(const f32x4*)(bias + ot * 128 + ow * 64 + x * 16 + q4 * 4);
#pragma unroll
    for (int y = 0; y < 4; ++y)
#pragma unroll
      for (int r = 0; r < 4; ++r)
        Ls[ow * 64 + x * 16 + q4 * 4 + r][nw * 64 + y * 16 + i16] = (f16)((acc[x][y][r] + bb[r]) * scl);
  }
  __syncthreads();
  if (proj < 2) {
    // o = 8*d + h ; write [b][h][n][d] (d-contiguous 32B runs)
    f16* dst = (proj == 0) ? Qt : Kt;
#pragma unroll
    for (int rnd = 0; rnd < 4; ++rnd) {
      int task = rnd * 256 + t;
      int nl = task & 127, h = task >> 7;
      f16x8 g0, g1;
#pragma unroll
      for (int j = 0; j < 8; ++j) g0[j] = Ls[8 * j + h][nl];
#pragma unroll
      for (int j = 0; j < 8; ++j) g1[j] = Ls[8 * (8 + j) + h][nl];
      f16* dp = dst + (((size_t)(b * 8 + h)) * SEQ + ntile * 128 + nl) * HD + ot * 16;
      *(f16x8*)dp = g0;
      *(f16x8*)(dp + 8) = g1;
    }
  } else {
    // V: write rows [b][h][d][m] (m-contiguous)
#pragma unroll
    for (int p = 0; p < 8; ++p) {
      int ol = (t >> 4) + 16 * p;
      int ch = t & 15;
      int og = ot * 128 + ol;
      int h = og & 7, d = og >> 3;
      f16* dp = Vh + (((size_t)(b * 8 + h)) * HD + d) * SEQ + ntile * 128 + ch * 8;
      *(f32x4*)dp = *(const f32x4*)&Ls[ol][ch * 8];
    }
  }
}

// ---------------------------------------------------------------- K2: flash attention, 128 q-rows/block
__global__ __launch_bounds__(256, 4) void k_attn(
    const f16* __restrict__ Qt, const f16* __restrict__ Kt, const f16* __restrict__ Vh,
    const float* __restrict__ qmask, const float* __restrict__ kvmask,
    f16* __restrict__ O)
{
  __shared__ __align__(16) char smem[18688];
  f16 (*Qs)[72] = (f16(*)[72])smem;            // [128][72] staging (aliased with Ks/Vs)
  f16 (*Ks)[72] = (f16(*)[72])smem;            // [64][72]
  f16 (*Vs)[72] = (f16(*)[72])(smem + 9216);   // [64][72]
  float* kvb = (float*)(smem + 18432);         // [64]

  int t = threadIdx.x;
  int bh = blockIdx.x >> 4;
  int b = bh >> 3;
  int n0 = (blockIdx.x & 15) * 128;
  int w = t >> 6, ln = t & 63, i16 = ln & 15, q4 = ln >> 4;

  const f16* Qb = Qt + (size_t)bh * SEQ * HD;
  const f16* Kb = Kt + (size_t)bh * SEQ * HD;
  const f16* Vb = Vh + (size_t)bh * HD * SEQ;

  // stage Q tile [128][64], pull frags to regs, then LDS is reused for K/V
#pragma unroll
  for (int p = 0; p < 4; ++p) {
    int row = (t >> 3) + 32 * p, ch = t & 7;
    *(f32x4*)&Qs[row][ch * 8] = *(const f32x4*)(Qb + ((size_t)(n0 + row)) * HD + ch * 8);
  }
  __syncthreads();
  f16x8 qf[2][2];
#pragma unroll
  for (int nt = 0; nt < 2; ++nt)
#pragma unroll
    for (int kc = 0; kc < 2; ++kc)
      qf[nt][kc] = *(const f16x8*)&Qs[w * 32 + nt * 16 + i16][kc * 32 + q4 * 8];
  float qok[2];
#pragma unroll
  for (int nt = 0; nt < 2; ++nt)
    qok[nt] = qmask[(size_t)b * SEQ + n0 + w * 32 + nt * 16 + i16];

  f32x4 acc_o[4][2];  // [dt][nt] — O^T fragments
#pragma unroll
  for (int dt = 0; dt < 4; ++dt)
#pragma unroll
    for (int nt = 0; nt < 2; ++nt) acc_o[dt][nt] = (f32x4){0.f, 0.f, 0.f, 0.f};
  float m_i[2] = {-3e38f, -3e38f};
  float l_i[2] = {0.f, 0.f};

  for (int it = 0; it < 32; ++it) {
    int m0 = it * 64;
    __syncthreads();
#pragma unroll
    for (int p = 0; p < 2; ++p) {
      int row = (t >> 3) + 32 * p, ch = t & 7;
      *(f32x4*)&Ks[row][ch * 8] = *(const f32x4*)(Kb + ((size_t)(m0 + row)) * HD + ch * 8);
      *(f32x4*)&Vs[row][ch * 8] = *(const f32x4*)(Vb + ((size_t)row) * SEQ + m0 + ch * 8);
    }
    if (t < 64) {
      float kv = kvmask[(size_t)b * SEQ + m0 + t];
      kvb[t] = (kv > 0.f) ? 0.f : KVNEG;
    }
    __syncthreads();

    f16x8 kf[4][2];
#pragma unroll
    for (int mt = 0; mt < 4; ++mt)
#pragma unroll
      for (int kc = 0; kc < 2; ++kc)
        kf[mt][kc] = *(const f16x8*)&Ks[mt * 16 + i16][kc * 32 + q4 * 8];
    f32x4 kvf[4];
#pragma unroll
    for (int mt = 0; mt < 4; ++mt) kvf[mt] = *(const f32x4*)&kvb[mt * 16 + q4 * 4];

    f16x4 pf[4][2];  // [mt][nt] — B-fragments for 16x16x16 PV, straight from C-layout
    float al[2];
#pragma unroll
    for (int nt = 0; nt < 2; ++nt) {
      // S^T[m][n] in log2 domain, kv bias via C-init (rows = key pos quad*4+r)
      f32x4 s[4];
#pragma unroll
      for (int mt = 0; mt < 4; ++mt) {
        f32x4 a = kvf[mt];
        a = __builtin_amdgcn_mfma_f32_16x16x32_f16(kf[mt][0], qf[nt][0], a, 0, 0, 0);
        a = __builtin_amdgcn_mfma_f32_16x16x32_f16(kf[mt][1], qf[nt][1], a, 0, 0, 0);
        s[mt] = a;
      }
      bool qz = qok[nt] > 0.f;
      float mx = -3e38f;
#pragma unroll
      for (int mt = 0; mt < 4; ++mt)
#pragma unroll
        for (int r = 0; r < 4; ++r) {
          float sv = qz ? s[mt][r] : KVNEG;
          s[mt][r] = sv;
          mx = fmaxf(mx, sv);
        }
      mx = fmaxf(mx, __shfl_xor(mx, 16, 64));
      mx = fmaxf(mx, __shfl_xor(mx, 32, 64));
      float mnew = fmaxf(m_i[nt], mx);
      float alpha = __builtin_amdgcn_exp2f(m_i[nt] - mnew);
      float rsum = 0.f;
#pragma unroll
      for (int mt = 0; mt < 4; ++mt) {
        float p0 = __builtin_amdgcn_exp2f(s[mt][0] - mnew);
        float p1 = __builtin_amdgcn_exp2f(s[mt][1] - mnew);
        float p2 = __builtin_amdgcn_exp2f(s[mt][2] - mnew);
        float p3 = __builtin_amdgcn_exp2f(s[mt][3] - mnew);
        rsum += (p0 + p1) + (p2 + p3);
        f16x4 pv;
        pv[0] = (f16)p0; pv[1] = (f16)p1; pv[2] = (f16)p2; pv[3] = (f16)p3;
        pf[mt][nt] = pv;
      }
      rsum += __shfl_xor(rsum, 16, 64);
      rsum += __shfl_xor(rsum, 32, 64);
      l_i[nt] = l_i[nt] * alpha + rsum;
      m_i[nt] = mnew;
      al[nt] = alpha;
    }

    f16x4 vf[4][4];  // [dt][mt] — A-fragments (V^T)
#pragma unroll
    for (int dt = 0; dt < 4; ++dt)
#pragma unroll
      for (int mt = 0; mt < 4; ++mt)
        vf[dt][mt] = *(const f16x4*)&Vs[dt * 16 + i16][mt * 16 + q4 * 4];

#pragma unroll
    for (int dt = 0; dt < 4; ++dt)
#pragma unroll
      for (int nt = 0; nt < 2; ++nt) {
        f32x4 o = acc_o[dt][nt];
        float a = al[nt];
#pragma unroll
        for (int r = 0; r < 4; ++r) o[r] *= a;
#pragma unroll
        for (int mt = 0; mt < 4; ++mt)
          o = __builtin_amdgcn_mfma_f32_16x16x16f16(vf[dt][mt], pf[mt][nt], o, 0, 0, 0);
        acc_o[dt][nt] = o;
      }
  }

  // epilogue: normalize, LDS transpose, coalesced row stores of O[b][h][n][d]
  __syncthreads();
  f16 (*Os)[72] = (f16(*)[72])(smem + w * 4608);   // [32][72] per wave
#pragma unroll
  for (int nt = 0; nt < 2; ++nt) {
    float inv = 1.f / l_i[nt];
#pragma unroll
    for (int dt = 0; dt < 4; ++dt) {
      f16x4 o4;
#pragma unroll
      for (int r = 0; r < 4; ++r) o4[r] = (f16)(acc_o[dt][nt][r] * inv);
      *(f16x4*)&Os[nt * 16 + i16][dt * 16 + q4 * 4] = o4;
    }
  }
  __syncthreads();
  f16* Ob = O + ((size_t)bh * SEQ + n0 + w * 32) * HD;
#pragma unroll
  for (int p = 0; p < 4; ++p) {
    int row = (ln >> 3) + 8 * p, ch = ln & 7;
    *(f32x4*)(Ob + (size_t)row * HD + ch * 8) = *(const f32x4*)&Os[row][ch * 8];
  }
}

// ---------------------------------------------------------------- K3: out = sum_h Wmh[h] @ O_h + bm  (fp32 out)
__global__ __launch_bounds__(256, 2) void k_out(
    const f16* __restrict__ Wmh, const float* __restrict__ bm,
    const f16* __restrict__ O, float* __restrict__ out)
{
  __shared__ __align__(16) char smem[20480];
  f16 (*As)[40] = (f16(*)[40])smem;
  f16 (*Bs)[40] = (f16(*)[40])(smem + 10240);

  int t = threadIdx.x;
  int b = blockIdx.y;
  int ot = blockIdx.x & 3, ntile = blockIdx.x >> 2;
  int w = t >> 6, ln = t & 63, i16 = ln & 15, q4 = ln >> 4;
  int ow = w >> 1, nw = w & 1;

  f32x4 acc[4][4];
#pragma unroll
  for (int x = 0; x < 4; ++x)
#pragma unroll
    for (int y = 0; y < 4; ++y) acc[x][y] = (f32x4){0.f, 0.f, 0.f, 0.f};

  int srow = t >> 1, sseg = t & 1;
  for (int ck = 0; ck < 16; ++ck) {
    int h = ck >> 1, dc = ck & 1;
    __syncthreads();
    const f16* Ap = Wmh + ((size_t)h * 512 + ot * 128 + srow) * 64 + dc * 32 + sseg * 16;
    *(f32x4*)&As[srow][sseg * 16] = *(const f32x4*)(Ap);
    *(f32x4*)&As[srow][sseg * 16 + 8] = *(const f32x4*)(Ap + 8);
    const f16* Bp = O + (((size_t)(b * 8 + h)) * SEQ + ntile * 128 + srow) * 64 + dc * 32 + sseg * 16;
    *(f32x4*)&Bs[srow][sseg * 16] = *(const f32x4*)(Bp);
    *(f32x4*)&Bs[srow][sseg * 16 + 8] = *(const f32x4*)(Bp + 8);
    __syncthreads();
    f16x8 af[4], bf[4];
#pragma unroll
    for (int x = 0; x < 4; ++x) af[x] = *(const f16x8*)&As[ow * 64 + x * 16 + i16][q4 * 8];
#pragma unroll
    for (int y = 0; y < 4; ++y) bf[y] = *(const f16x8*)&Bs[nw * 64 + y * 16 + i16][q4 * 8];
#pragma unroll
    for (int x = 0; x < 4; ++x)
#pragma unroll
      for (int y = 0; y < 4; ++y)
        acc[x][y] = __builtin_amdgcn_mfma_f32_16x16x32_f16(af[x], bf[y], acc[x][y], 0, 0, 0);
  }

#pragma unroll
  for (int x = 0; x < 4; ++x) {
    f32x4 bb = *(const f32x4*)(bm + ot * 128 + ow * 64 + x * 16 + q4 * 4);
#pragma unroll
    for (int y = 0; y < 4; ++y)
#pragma unroll
      for (int r = 0; r < 4; ++r) {
        int o_g = ot * 128 + ow * 64 + x * 16 + q4 * 4 + r;
        int n_g = ntile * 128 + nw * 64 + y * 16 + i16;
        out[((size_t)b * 512 + o_g) * SEQ + n_g] = acc[x][y][r] + bb[r];
      }
  }
}

// ----------------------------------------------------------------
extern "C" void kernel_launch(void* const* d_in, const int* in_sizes, int n_in,
                              void* d_out, int out_size, void* d_ws, size_t ws_size,
                              hipStream_t stream)
{
  const float* query  = (const float*)d_in[0];
  const float* key    = (const float*)d_in[1];
  const float* value  = (const float*)d_in[2];
  const float* qmask  = (const float*)d_in[3];
  const float* kvmask = (const float*)d_in[4];
  const float* Wq = (const float*)d_in[5];
  const float* bq = (const float*)d_in[6];
  const float* Wk = (const float*)d_in[7];
  const float* bk = (const float*)d_in[8];
  const float* Wv = (const float*)d_in[9];
  const float* bv = (const float*)d_in[10];
  const float* Wm = (const float*)d_in[11];
  const float* bm = (const float*)d_in[12];
  float* out = (float*)d_out;

  char* ws = (char*)d_ws;
  f16* XT  = (f16*)(ws);                  // [3][8][2048][512]  50,331,648 B
  f16* Qt  = (f16*)(ws + 50331648);       // [8][8][2048][64]   16,777,216 B
  f16* Kt  = (f16*)(ws + 67108864);
  f16* Vh  = (f16*)(ws + 83886080);       // [8][8][64][2048]
  f16* Oat = (f16*)(ws);                  // alias XT_q region (XT dead after k_proj)
  f16* W3  = (f16*)(ws + 100663296);      // [3][512][512]       1,572,864 B
  f16* Wmh = (f16*)(ws + 102236160);      // [8][512][64]          524,288 B

  k_transpose<<<dim3(32, 8, 24), 256, 0, stream>>>(query, key, value, XT);
  k_wconv<<<1024, 256, 0, stream>>>(Wq, Wk, Wv, Wm, W3, Wmh);
  k_proj<<<dim3(64, 8, 3), 256, 0, stream>>>(W3, bq, bk, bv, XT, Qt, Kt, Vh);
  k_attn<<<1024, 256, 0, stream>>>(Qt, Kt, Vh, qmask, kvmask, Oat);
  k_out<<<dim3(64, 8), 256, 0, stream>>>(Wmh, bm, Oat, out);
}